// Round 2
// baseline (170.855 us; speedup 1.0000x reference)
//
#include <hip/hip_runtime.h>
#include <hip/hip_bf16.h>

// Problem constants
#define B_ 2
#define C_ 256
#define O_ 256
#define T_ 16
#define H_ 64
#define W_ 64

typedef __bf16 bf16x8 __attribute__((ext_vector_type(8)));
typedef float  f32x4  __attribute__((ext_vector_type(4)));

// ws layout:
//   [0, 131072)       : W3d bf16 pre-swizzled LDS image: [mt(2)][o_l*512 + ((cg*16)^((o_l&7)<<4))]
//   [131072, 163840)  : obj f32 [b][o][t]  (B*O*T = 8192 floats)
#define WS_OBJ_OFF 131072

__device__ __forceinline__ void gload_lds16(const void* g, void* l) {
    __builtin_amdgcn_global_load_lds(
        (const __attribute__((address_space(1))) void*)g,
        (__attribute__((address_space(3))) void*)l, 16, 0, 0);
}
__device__ __forceinline__ void gload_lds4(const void* g, void* l) {
    __builtin_amdgcn_global_load_lds(
        (const __attribute__((address_space(1))) void*)g,
        (__attribute__((address_space(3))) void*)l, 4, 0, 0);
}

// ---------------- prep kernel ----------------
// blocks 0..31  : obj[b,o,t] = sum_c W1d[o,c]*fea_obj[b,c,t] + b1d[o]
// blocks 32..63 : W3d -> bf16 pre-swizzled image in ws ([128 o][256 c] rows of 512B,
//                 XOR-swizzle within each 128B sub-block)
__global__ __launch_bounds__(256) void prep_kernel(
    const float* __restrict__ fea_obj, const float* __restrict__ W3d,
    const float* __restrict__ W1d, const float* __restrict__ b1d,
    __bf16* __restrict__ wsA, float* __restrict__ wsObj) {
    const int bid = blockIdx.x;
    const int tid = threadIdx.x;
    if (bid < 32) {
        const int b = bid >> 4, t = bid & 15;
        __shared__ float fo[C_];
        fo[tid] = fea_obj[(b * C_ + tid) * T_ + t];
        __syncthreads();
        const int o = tid;
        const float4* wrow = (const float4*)(W1d + o * C_);
        float s = 0.f;
#pragma unroll 8
        for (int cq = 0; cq < C_ / 4; ++cq) {
            float4 wv = wrow[cq];
            s += wv.x * fo[cq * 4 + 0] + wv.y * fo[cq * 4 + 1] +
                 wv.z * fo[cq * 4 + 2] + wv.w * fo[cq * 4 + 3];
        }
        wsObj[(b * O_ + o) * T_ + t] = s + b1d[o];
    } else {
        // 8192 groups of 8 consecutive c
        const int g = (bid - 32) * 256 + tid;
        const int o = g >> 5;        // 0..255
        const int cg = g & 31;       // group of 8 c's
        const float* sp = W3d + o * C_ + cg * 8;
        float4 a0 = *(const float4*)sp;
        float4 a1 = *(const float4*)(sp + 4);
        bf16x8 pk;
        pk[0] = (__bf16)a0.x; pk[1] = (__bf16)a0.y;
        pk[2] = (__bf16)a0.z; pk[3] = (__bf16)a0.w;
        pk[4] = (__bf16)a1.x; pk[5] = (__bf16)a1.y;
        pk[6] = (__bf16)a1.z; pk[7] = (__bf16)a1.w;
        const int mt = o >> 7, o_l = o & 127;
        const int dstb = mt * 65536 + o_l * 512 + ((cg * 16) ^ ((o_l & 7) << 4));
        *(bf16x8*)((char*)wsA + dstb) = pk;
    }
}

// ---------------- main kernel ----------------
// Grid 512 = hg(8) x mt(2) x bt(32). Block: 256 thr (4 waves, 2m x 2n).
// Block tile: 128 o (mt half) x 64 w (all) x 8 h, K=256 fully in LDS (A) /
// registers (tw as bf16 B-frags). Per h: rescale B-frags by th, 8 k-steps,
// fused epilogue.
__global__ __launch_bounds__(256, 2) void main_kernel(
    const float* __restrict__ fea_th, const float* __restrict__ fea_tw,
    const float* __restrict__ heatmap, const float* __restrict__ mask,
    const float* __restrict__ b3d,
    const __bf16* __restrict__ wsA, const float* __restrict__ wsObj,
    float* __restrict__ out) {
    extern __shared__ char smem[];          // 65536 (sA) + 8192 (sTh) = 73728
    char*  sA  = smem;                      // [128 o][256 c] bf16, 512B rows, swizzled
    float* sTh = (float*)(smem + 65536);    // [8 h][256 c] f32

    const int tid  = threadIdx.x;
    const int lane = tid & 63;
    const int wv   = tid >> 6;
    const int wv_m = wv >> 1;
    const int wv_n = wv & 1;
    const int kgrp = lane >> 4;
    const int l15  = lane & 15;

    const int bid = blockIdx.x;
    const int hg = bid & 7, mt = (bid >> 3) & 1, bt = bid >> 4;
    const int b = bt >> 4, t = bt & 15, h0 = hg * 8;

    // ---- stage A: 64 KiB, pre-swizzled image, pure linear gload_lds ----
    const char* imgA = (const char*)wsA + mt * 65536;
#pragma unroll
    for (int q = 0; q < 16; ++q)
        gload_lds16(imgA + q * 4096 + tid * 16, sA + q * 4096 + tid * 16);

    // ---- stage th: [8 h][256 c] f32, per-lane-src gload_lds w4 ----
#pragma unroll
    for (int g = 0; g < 8; ++g) {
        const int gr = g * 4 + wv;          // 0..31
        const int s  = gr * 64 + lane;      // 0..2047
        const int hl = s >> 8, c = s & 255;
        gload_lds4(fea_th + ((b * C_ + c) * T_ + t) * H_ + h0 + hl,
                   (char*)sTh + gr * 256 + lane * 4);
    }

    // ---- tw -> register B-frags (bf16), loaded once ----
    const int wcol0 = wv_n * 32 + l15;
    const float* twp = fea_tw + ((b * C_) * T_ + t) * W_;
    bf16x8 twf[2][8];
#pragma unroll
    for (int n = 0; n < 2; ++n)
#pragma unroll
        for (int ks = 0; ks < 8; ++ks) {
            bf16x8 pk;
#pragma unroll
            for (int j = 0; j < 8; ++j) {
                const int c = ks * 32 + kgrp * 8 + j;
                pk[j] = (__bf16)twp[c * (T_ * W_) + wcol0 + n * 16];
            }
            twf[n][ks] = pk;
        }

    // ---- per-o epilogue constants ----
    const int obase = mt * 128 + wv_m * 64 + kgrp * 4;
    float pb[16], pobj[16];
#pragma unroll
    for (int m = 0; m < 4; ++m)
#pragma unroll
        for (int r = 0; r < 4; ++r) {
            const int o = obase + m * 16 + r;
            pb[m * 4 + r]   = b3d[o];
            pobj[m * 4 + r] = wsObj[(b * O_ + o) * T_ + t];
        }

    __syncthreads();   // drains gload_lds (vmcnt) + makes sA/sTh visible

    const int hmb = (b * T_ + t) * (H_ * W_);
    const int swz = (l15 & 7) << 4;

    for (int hl = 0; hl < 8; ++hl) {
        // prefetch heatmap/mask for this h (latency hidden by K-loop)
        const int hrow = hmb + (h0 + hl) * W_ + wcol0;
        const float ht0 = heatmap[hrow],      ht1 = heatmap[hrow + 16];
        const float mk0 = mask[hrow],         mk1 = mask[hrow + 16];

        f32x4 acc[4][2] = {};
#pragma unroll
        for (int ks = 0; ks < 8; ++ks) {
            // th slice for this lane's k-slots (broadcast within 16-lane groups)
            const float* thp = sTh + hl * 256 + ks * 32 + kgrp * 8;
            const f32x4 th0 = *(const f32x4*)thp;
            const f32x4 th1 = *(const f32x4*)(thp + 4);

            // A fragments from swizzled LDS
            bf16x8 af[4];
#pragma unroll
            for (int m = 0; m < 4; ++m) {
                const int row = wv_m * 64 + m * 16 + l15;
                af[m] = *(const bf16x8*)(sA + row * 512 +
                                         ((ks * 64 + kgrp * 16) ^ swz));
            }

            // B fragments: tw (bf16 regs) x th (f32)
            bf16x8 bfr[2];
#pragma unroll
            for (int n = 0; n < 2; ++n) {
                const bf16x8 tw8 = twf[n][ks];
                bf16x8 pk;
                pk[0] = (__bf16)((float)tw8[0] * th0[0]);
                pk[1] = (__bf16)((float)tw8[1] * th0[1]);
                pk[2] = (__bf16)((float)tw8[2] * th0[2]);
                pk[3] = (__bf16)((float)tw8[3] * th0[3]);
                pk[4] = (__bf16)((float)tw8[4] * th1[0]);
                pk[5] = (__bf16)((float)tw8[5] * th1[1]);
                pk[6] = (__bf16)((float)tw8[6] * th1[2]);
                pk[7] = (__bf16)((float)tw8[7] * th1[3]);
                bfr[n] = pk;
            }

#pragma unroll
            for (int m = 0; m < 4; ++m)
#pragma unroll
                for (int n = 0; n < 2; ++n)
                    acc[m][n] = __builtin_amdgcn_mfma_f32_16x16x32_bf16(
                        af[m], bfr[n], acc[m][n], 0, 0, 0);
        }

        // ---- fused epilogue ----
#pragma unroll
        for (int m = 0; m < 4; ++m)
#pragma unroll
            for (int r = 0; r < 4; ++r) {
                const int o = obase + m * 16 + r;
                float* orow = out + (((size_t)(b * O_ + o) * T_ + t) * H_ +
                                     h0 + hl) * W_;
                float v0 = acc[m][0][r] + pb[m * 4 + r];
                v0 = v0 * (1.f - ht0) + pobj[m * 4 + r] * ht0;
                orow[wcol0] = v0 * mk0;
                float v1 = acc[m][1][r] + pb[m * 4 + r];
                v1 = v1 * (1.f - ht1) + pobj[m * 4 + r] * ht1;
                orow[wcol0 + 16] = v1 * mk1;
            }
    }
}

extern "C" void kernel_launch(void* const* d_in, const int* in_sizes, int n_in,
                              void* d_out, int out_size, void* d_ws, size_t ws_size,
                              hipStream_t stream) {
    const float* fea_th  = (const float*)d_in[0];
    const float* fea_tw  = (const float*)d_in[1];
    const float* fea_obj = (const float*)d_in[2];
    const float* heatmap = (const float*)d_in[3];
    const float* mask    = (const float*)d_in[4];
    const float* W3d     = (const float*)d_in[5];
    const float* b3d     = (const float*)d_in[6];
    const float* W1d     = (const float*)d_in[7];
    const float* b1d     = (const float*)d_in[8];
    float* out = (float*)d_out;

    __bf16* wsA  = (__bf16*)d_ws;
    float* wsObj = (float*)((char*)d_ws + WS_OBJ_OFF);

    hipLaunchKernelGGL(prep_kernel, dim3(64), dim3(256), 0, stream,
                       fea_obj, W3d, W1d, b1d, wsA, wsObj);
    hipLaunchKernelGGL(main_kernel, dim3(512), dim3(256), 73728, stream,
                       fea_th, fea_tw, heatmap, mask, b3d, wsA, wsObj, out);
}

// Round 3
// 144.414 us; speedup vs baseline: 1.1831x; 1.1831x over previous
//
#include <hip/hip_runtime.h>
#include <hip/hip_bf16.h>

// Problem constants
#define B_ 2
#define C_ 256
#define O_ 256
#define T_ 16
#define H_ 64
#define W_ 64

typedef __bf16 bf16x8 __attribute__((ext_vector_type(8)));
typedef float  f32x4  __attribute__((ext_vector_type(4)));

// ws layout:
//   [0, 131072)       : W3d bf16 pre-swizzled LDS image: [mt(2)][o_l*512 + ((cg*16)^((o_l&7)<<4))]
//   [131072, 163840)  : obj f32 [b][t][o]  (B*T*O = 8192 floats, contiguous in o)
#define WS_OBJ_OFF 131072

__device__ __forceinline__ void gload_lds16(const void* g, void* l) {
    __builtin_amdgcn_global_load_lds(
        (const __attribute__((address_space(1))) void*)g,
        (__attribute__((address_space(3))) void*)l, 16, 0, 0);
}
__device__ __forceinline__ void gload_lds4(const void* g, void* l) {
    __builtin_amdgcn_global_load_lds(
        (const __attribute__((address_space(1))) void*)g,
        (__attribute__((address_space(3))) void*)l, 4, 0, 0);
}

// ---------------- prep kernel ----------------
// blocks 0..31  : obj[b,t,o] = sum_c W1d[o,c]*fea_obj[b,c,t] + b1d[o]
// blocks 32..63 : W3d -> bf16 pre-swizzled image in ws ([128 o][256 c] rows of 512B,
//                 XOR-swizzle within each 128B sub-block)
__global__ __launch_bounds__(256) void prep_kernel(
    const float* __restrict__ fea_obj, const float* __restrict__ W3d,
    const float* __restrict__ W1d, const float* __restrict__ b1d,
    __bf16* __restrict__ wsA, float* __restrict__ wsObj) {
    const int bid = blockIdx.x;
    const int tid = threadIdx.x;
    if (bid < 32) {
        const int b = bid >> 4, t = bid & 15;
        __shared__ float fo[C_];
        fo[tid] = fea_obj[(b * C_ + tid) * T_ + t];
        __syncthreads();
        const int o = tid;
        const float4* wrow = (const float4*)(W1d + o * C_);
        float s = 0.f;
#pragma unroll 8
        for (int cq = 0; cq < C_ / 4; ++cq) {
            float4 wv = wrow[cq];
            s += wv.x * fo[cq * 4 + 0] + wv.y * fo[cq * 4 + 1] +
                 wv.z * fo[cq * 4 + 2] + wv.w * fo[cq * 4 + 3];
        }
        wsObj[(b * T_ + t) * O_ + o] = s + b1d[o];   // [b][t][o] layout
    } else {
        // 8192 groups of 8 consecutive c
        const int g = (bid - 32) * 256 + tid;
        const int o = g >> 5;        // 0..255
        const int cg = g & 31;       // group of 8 c's
        const float* sp = W3d + o * C_ + cg * 8;
        float4 a0 = *(const float4*)sp;
        float4 a1 = *(const float4*)(sp + 4);
        bf16x8 pk;
        pk[0] = (__bf16)a0.x; pk[1] = (__bf16)a0.y;
        pk[2] = (__bf16)a0.z; pk[3] = (__bf16)a0.w;
        pk[4] = (__bf16)a1.x; pk[5] = (__bf16)a1.y;
        pk[6] = (__bf16)a1.z; pk[7] = (__bf16)a1.w;
        const int mt = o >> 7, o_l = o & 127;
        const int dstb = mt * 65536 + o_l * 512 + ((cg * 16) ^ ((o_l & 7) << 4));
        *(bf16x8*)((char*)wsA + dstb) = pk;
    }
}

// ---------------- main kernel ----------------
// Grid 512 = hg(8) x mt(2) x bt(32). Block: 256 thr (4 waves, 2m x 2n).
// Block tile: 128 o (mt half) x 64 w (all) x 8 h, K=256 fully in LDS (A) /
// registers (tw as bf16 B-frags). Per h: rescale B-frags by th, 8 k-steps,
// fused epilogue. waves_per_eu pinned to 2 (LDS caps us there anyway) so the
// compiler gets the full 256-VGPR budget -> no spills.
__global__ __attribute__((amdgpu_waves_per_eu(2, 2))) __launch_bounds__(256)
void main_kernel(
    const float* __restrict__ fea_th, const float* __restrict__ fea_tw,
    const float* __restrict__ heatmap, const float* __restrict__ mask,
    const float* __restrict__ b3d,
    const __bf16* __restrict__ wsA, const float* __restrict__ wsObj,
    float* __restrict__ out) {
    extern __shared__ char smem[];          // 65536 (sA) + 8192 (sTh) = 73728
    char*  sA  = smem;                      // [128 o][256 c] bf16, 512B rows, swizzled
    float* sTh = (float*)(smem + 65536);    // [8 h][256 c] f32

    const int tid  = threadIdx.x;
    const int lane = tid & 63;
    const int wv   = tid >> 6;
    const int wv_m = wv >> 1;
    const int wv_n = wv & 1;
    const int kgrp = lane >> 4;
    const int l15  = lane & 15;

    const int bid = blockIdx.x;
    const int hg = bid & 7, mt = (bid >> 3) & 1, bt = bid >> 4;
    const int b = bt >> 4, t = bt & 15, h0 = hg * 8;

    // ---- stage A: 64 KiB, pre-swizzled image, pure linear gload_lds ----
    const char* imgA = (const char*)wsA + mt * 65536;
#pragma unroll
    for (int q = 0; q < 16; ++q)
        gload_lds16(imgA + q * 4096 + tid * 16, sA + q * 4096 + tid * 16);

    // ---- stage th: [8 h][256 c] f32, per-lane-src gload_lds w4 ----
#pragma unroll
    for (int g = 0; g < 8; ++g) {
        const int gr = g * 4 + wv;          // 0..31
        const int s  = gr * 64 + lane;      // 0..2047
        const int hl = s >> 8, c = s & 255;
        gload_lds4(fea_th + ((b * C_ + c) * T_ + t) * H_ + h0 + hl,
                   (char*)sTh + gr * 256 + lane * 4);
    }

    // ---- tw -> register B-frags (bf16), loaded once ----
    const int wcol0 = wv_n * 32 + l15;
    const float* twp = fea_tw + ((b * C_) * T_ + t) * W_;
    bf16x8 twf[2][8];
#pragma unroll
    for (int n = 0; n < 2; ++n)
#pragma unroll
        for (int ks = 0; ks < 8; ++ks) {
            bf16x8 pk;
#pragma unroll
            for (int j = 0; j < 8; ++j) {
                const int c = ks * 32 + kgrp * 8 + j;
                pk[j] = (__bf16)twp[c * (T_ * W_) + wcol0 + n * 16];
            }
            twf[n][ks] = pk;
        }

    // ---- per-o epilogue constants (vector loads, contiguous in o) ----
    const int obase = mt * 128 + wv_m * 64 + kgrp * 4;
    f32x4 pb[4], pobj[4];
    const float* objp = wsObj + (b * T_ + t) * O_;
#pragma unroll
    for (int m = 0; m < 4; ++m) {
        pb[m]   = *(const f32x4*)(b3d + obase + m * 16);
        pobj[m] = *(const f32x4*)(objp + obase + m * 16);
    }

    __syncthreads();   // drains gload_lds (vmcnt) + makes sA/sTh visible

    const int hmb = (b * T_ + t) * (H_ * W_);
    const int swz = (l15 & 7) << 4;

    for (int hl = 0; hl < 8; ++hl) {
        // prefetch heatmap/mask for this h (latency hidden by K-loop)
        const int hrow = hmb + (h0 + hl) * W_ + wcol0;
        const float ht0 = heatmap[hrow],      ht1 = heatmap[hrow + 16];
        const float mk0 = mask[hrow],         mk1 = mask[hrow + 16];

        f32x4 acc[4][2] = {};
#pragma unroll
        for (int ks = 0; ks < 8; ++ks) {
            // th slice for this lane's k-slots (broadcast within 16-lane groups)
            const float* thp = sTh + hl * 256 + ks * 32 + kgrp * 8;
            const f32x4 th0 = *(const f32x4*)thp;
            const f32x4 th1 = *(const f32x4*)(thp + 4);

            // A fragments from swizzled LDS
            bf16x8 af[4];
#pragma unroll
            for (int m = 0; m < 4; ++m) {
                const int row = wv_m * 64 + m * 16 + l15;
                af[m] = *(const bf16x8*)(sA + row * 512 +
                                         ((ks * 64 + kgrp * 16) ^ swz));
            }

            // B fragments: tw (bf16 regs) x th (f32)
            bf16x8 bfr[2];
#pragma unroll
            for (int n = 0; n < 2; ++n) {
                const bf16x8 tw8 = twf[n][ks];
                bf16x8 pk;
                pk[0] = (__bf16)((float)tw8[0] * th0[0]);
                pk[1] = (__bf16)((float)tw8[1] * th0[1]);
                pk[2] = (__bf16)((float)tw8[2] * th0[2]);
                pk[3] = (__bf16)((float)tw8[3] * th0[3]);
                pk[4] = (__bf16)((float)tw8[4] * th1[0]);
                pk[5] = (__bf16)((float)tw8[5] * th1[1]);
                pk[6] = (__bf16)((float)tw8[6] * th1[2]);
                pk[7] = (__bf16)((float)tw8[7] * th1[3]);
                bfr[n] = pk;
            }

#pragma unroll
            for (int m = 0; m < 4; ++m)
#pragma unroll
                for (int n = 0; n < 2; ++n)
                    acc[m][n] = __builtin_amdgcn_mfma_f32_16x16x32_bf16(
                        af[m], bfr[n], acc[m][n], 0, 0, 0);
        }

        // ---- fused epilogue ----
#pragma unroll
        for (int m = 0; m < 4; ++m)
#pragma unroll
            for (int r = 0; r < 4; ++r) {
                const int o = obase + m * 16 + r;
                float* orow = out + (((size_t)(b * O_ + o) * T_ + t) * H_ +
                                     h0 + hl) * W_;
                float v0 = acc[m][0][r] + pb[m][r];
                v0 = v0 * (1.f - ht0) + pobj[m][r] * ht0;
                orow[wcol0] = v0 * mk0;
                float v1 = acc[m][1][r] + pb[m][r];
                v1 = v1 * (1.f - ht1) + pobj[m][r] * ht1;
                orow[wcol0 + 16] = v1 * mk1;
            }
    }
}

extern "C" void kernel_launch(void* const* d_in, const int* in_sizes, int n_in,
                              void* d_out, int out_size, void* d_ws, size_t ws_size,
                              hipStream_t stream) {
    const float* fea_th  = (const float*)d_in[0];
    const float* fea_tw  = (const float*)d_in[1];
    const float* fea_obj = (const float*)d_in[2];
    const float* heatmap = (const float*)d_in[3];
    const float* mask    = (const float*)d_in[4];
    const float* W3d     = (const float*)d_in[5];
    const float* b3d     = (const float*)d_in[6];
    const float* W1d     = (const float*)d_in[7];
    const float* b1d     = (const float*)d_in[8];
    float* out = (float*)d_out;

    __bf16* wsA  = (__bf16*)d_ws;
    float* wsObj = (float*)((char*)d_ws + WS_OBJ_OFF);

    hipLaunchKernelGGL(prep_kernel, dim3(64), dim3(256), 0, stream,
                       fea_obj, W3d, W1d, b1d, wsA, wsObj);
    hipLaunchKernelGGL(main_kernel, dim3(512), dim3(256), 73728, stream,
                       fea_th, fea_tw, heatmap, mask, b3d, wsA, wsObj, out);
}

// Round 4
// 143.078 us; speedup vs baseline: 1.1941x; 1.0093x over previous
//
#include <hip/hip_runtime.h>
#include <hip/hip_bf16.h>

// Problem constants
#define B_ 2
#define C_ 256
#define O_ 256
#define T_ 16
#define H_ 64
#define W_ 64

typedef __bf16 bf16x8 __attribute__((ext_vector_type(8)));
typedef float  f32x4  __attribute__((ext_vector_type(4)));

// ws layout:
//   [0, 131072)       : W3d bf16 pre-swizzled LDS image: [mt(2)][o_l*512 + ((cg*16)^((o_l&7)<<4))]
//   [131072, 163840)  : obj f32 [b][t][o]  (B*T*O = 8192 floats, contiguous in o)
#define WS_OBJ_OFF 131072

__device__ __forceinline__ void gload_lds16(const void* g, void* l) {
    __builtin_amdgcn_global_load_lds(
        (const __attribute__((address_space(1))) void*)g,
        (__attribute__((address_space(3))) void*)l, 16, 0, 0);
}

// ---------------- prep kernel ----------------
// blocks 0..31  : obj[b,t,o] = sum_c W1d[o,c]*fea_obj[b,c,t] + b1d[o]
// blocks 32..63 : W3d -> bf16 pre-swizzled image in ws ([128 o][256 c] rows of 512B,
//                 XOR-swizzle within each 128B sub-block)
__global__ __launch_bounds__(256) void prep_kernel(
    const float* __restrict__ fea_obj, const float* __restrict__ W3d,
    const float* __restrict__ W1d, const float* __restrict__ b1d,
    __bf16* __restrict__ wsA, float* __restrict__ wsObj) {
    const int bid = blockIdx.x;
    const int tid = threadIdx.x;
    if (bid < 32) {
        const int b = bid >> 4, t = bid & 15;
        __shared__ float fo[C_];
        fo[tid] = fea_obj[(b * C_ + tid) * T_ + t];
        __syncthreads();
        const int o = tid;
        const float4* wrow = (const float4*)(W1d + o * C_);
        float s = 0.f;
#pragma unroll 8
        for (int cq = 0; cq < C_ / 4; ++cq) {
            float4 wv = wrow[cq];
            s += wv.x * fo[cq * 4 + 0] + wv.y * fo[cq * 4 + 1] +
                 wv.z * fo[cq * 4 + 2] + wv.w * fo[cq * 4 + 3];
        }
        wsObj[(b * T_ + t) * O_ + o] = s + b1d[o];   // [b][t][o] layout
    } else {
        // 8192 groups of 8 consecutive c
        const int g = (bid - 32) * 256 + tid;
        const int o = g >> 5;        // 0..255
        const int cg = g & 31;       // group of 8 c's
        const float* sp = W3d + o * C_ + cg * 8;
        float4 a0 = *(const float4*)sp;
        float4 a1 = *(const float4*)(sp + 4);
        bf16x8 pk;
        pk[0] = (__bf16)a0.x; pk[1] = (__bf16)a0.y;
        pk[2] = (__bf16)a0.z; pk[3] = (__bf16)a0.w;
        pk[4] = (__bf16)a1.x; pk[5] = (__bf16)a1.y;
        pk[6] = (__bf16)a1.z; pk[7] = (__bf16)a1.w;
        const int mt = o >> 7, o_l = o & 127;
        const int dstb = mt * 65536 + o_l * 512 + ((cg * 16) ^ ((o_l & 7) << 4));
        *(bf16x8*)((char*)wsA + dstb) = pk;
    }
}

// ---------------- main kernel ----------------
// Grid 512 = hg(8) x mt(2) x bt(32). Block: 256 thr (4 waves, 2m x 2n).
// Block tile: 128 o (mt half) x 64 w (all) x 8 h, K=256 fully in LDS (A) /
// registers (tw as bf16 B-frags). Per h: rescale B-frags by th, 8 k-steps,
// fused epilogue.
// STATIC 73728-B LDS -> backend sees 2 wg/CU -> 2 waves/EU -> 256-VGPR
// budget -> no spills (r2/r3 spilled: extern LDS hid the occupancy cap).
__global__ __attribute__((amdgpu_flat_work_group_size(256, 256),
                          amdgpu_waves_per_eu(2, 2)))
void main_kernel(
    const float* __restrict__ fea_th, const float* __restrict__ fea_tw,
    const float* __restrict__ heatmap, const float* __restrict__ mask,
    const float* __restrict__ b3d,
    const __bf16* __restrict__ wsA, const float* __restrict__ wsObj,
    float* __restrict__ out) {
    __shared__ __align__(16) char smem[73728];  // 65536 (sA) + 8192 (sTh)
    char*  sA  = smem;                      // [128 o][256 c] bf16, 512B rows, swizzled
    float* sTh = (float*)(smem + 65536);    // [8 h][256 c] f32

    const int tid  = threadIdx.x;
    const int lane = tid & 63;
    const int wv   = tid >> 6;
    const int wv_m = wv >> 1;
    const int wv_n = wv & 1;
    const int kgrp = lane >> 4;
    const int l15  = lane & 15;

    const int bid = blockIdx.x;
    const int hg = bid & 7, mt = (bid >> 3) & 1, bt = bid >> 4;
    const int b = bt >> 4, t = bt & 15, h0 = hg * 8;

    // ---- stage A: 64 KiB, pre-swizzled image, pure linear gload_lds ----
    const char* imgA = (const char*)wsA + mt * 65536;
#pragma unroll
    for (int q = 0; q < 16; ++q)
        gload_lds16(imgA + q * 4096 + tid * 16, sA + q * 4096 + tid * 16);

    // ---- stage th: thread tid owns c=tid, loads its 8-h chunk (32B) ----
    {
        const float* thp = fea_th + ((b * C_ + tid) * T_ + t) * H_ + h0;
        float4 v0 = *(const float4*)thp;
        float4 v1 = *(const float4*)(thp + 4);
        sTh[0 * 256 + tid] = v0.x;  sTh[1 * 256 + tid] = v0.y;
        sTh[2 * 256 + tid] = v0.z;  sTh[3 * 256 + tid] = v0.w;
        sTh[4 * 256 + tid] = v1.x;  sTh[5 * 256 + tid] = v1.y;
        sTh[6 * 256 + tid] = v1.z;  sTh[7 * 256 + tid] = v1.w;
    }

    // ---- tw -> register B-frags (bf16), loaded once ----
    const int wcol0 = wv_n * 32 + l15;
    const float* twp = fea_tw + ((b * C_) * T_ + t) * W_;
    bf16x8 twf[2][8];
#pragma unroll
    for (int n = 0; n < 2; ++n)
#pragma unroll
        for (int ks = 0; ks < 8; ++ks) {
            bf16x8 pk;
#pragma unroll
            for (int j = 0; j < 8; ++j) {
                const int c = ks * 32 + kgrp * 8 + j;
                pk[j] = (__bf16)twp[c * (T_ * W_) + wcol0 + n * 16];
            }
            twf[n][ks] = pk;
        }

    // ---- per-o epilogue constants (vector loads, contiguous in o) ----
    const int obase = mt * 128 + wv_m * 64 + kgrp * 4;
    f32x4 pb[4], pobj[4];
    const float* objp = wsObj + (b * T_ + t) * O_;
#pragma unroll
    for (int m = 0; m < 4; ++m) {
        pb[m]   = *(const f32x4*)(b3d + obase + m * 16);
        pobj[m] = *(const f32x4*)(objp + obase + m * 16);
    }

    __syncthreads();   // drains gload_lds (vmcnt) + ds_writes; sA/sTh visible

    const int hmb = (b * T_ + t) * (H_ * W_);
    const int swz = (l15 & 7) << 4;

    for (int hl = 0; hl < 8; ++hl) {
        // prefetch heatmap/mask for this h (latency hidden by K-loop)
        const int hrow = hmb + (h0 + hl) * W_ + wcol0;
        const float ht0 = heatmap[hrow],      ht1 = heatmap[hrow + 16];
        const float mk0 = mask[hrow],         mk1 = mask[hrow + 16];

        f32x4 acc[4][2] = {};
#pragma unroll
        for (int ks = 0; ks < 8; ++ks) {
            // th slice for this lane's k-slots (broadcast within 16-lane groups)
            const float* thp = sTh + hl * 256 + ks * 32 + kgrp * 8;
            const f32x4 th0 = *(const f32x4*)thp;
            const f32x4 th1 = *(const f32x4*)(thp + 4);

            // A fragments from swizzled LDS
            bf16x8 af[4];
#pragma unroll
            for (int m = 0; m < 4; ++m) {
                const int row = wv_m * 64 + m * 16 + l15;
                af[m] = *(const bf16x8*)(sA + row * 512 +
                                         ((ks * 64 + kgrp * 16) ^ swz));
            }

            // B fragments: tw (bf16 regs) x th (f32)
            bf16x8 bfr[2];
#pragma unroll
            for (int n = 0; n < 2; ++n) {
                const bf16x8 tw8 = twf[n][ks];
                bf16x8 pk;
                pk[0] = (__bf16)((float)tw8[0] * th0[0]);
                pk[1] = (__bf16)((float)tw8[1] * th0[1]);
                pk[2] = (__bf16)((float)tw8[2] * th0[2]);
                pk[3] = (__bf16)((float)tw8[3] * th0[3]);
                pk[4] = (__bf16)((float)tw8[4] * th1[0]);
                pk[5] = (__bf16)((float)tw8[5] * th1[1]);
                pk[6] = (__bf16)((float)tw8[6] * th1[2]);
                pk[7] = (__bf16)((float)tw8[7] * th1[3]);
                bfr[n] = pk;
            }

#pragma unroll
            for (int m = 0; m < 4; ++m)
#pragma unroll
                for (int n = 0; n < 2; ++n)
                    acc[m][n] = __builtin_amdgcn_mfma_f32_16x16x32_bf16(
                        af[m], bfr[n], acc[m][n], 0, 0, 0);
        }

        // ---- fused epilogue ----
#pragma unroll
        for (int m = 0; m < 4; ++m)
#pragma unroll
            for (int r = 0; r < 4; ++r) {
                const int o = obase + m * 16 + r;
                float* orow = out + (((size_t)(b * O_ + o) * T_ + t) * H_ +
                                     h0 + hl) * W_;
                float v0 = acc[m][0][r] + pb[m][r];
                v0 = v0 * (1.f - ht0) + pobj[m][r] * ht0;
                orow[wcol0] = v0 * mk0;
                float v1 = acc[m][1][r] + pb[m][r];
                v1 = v1 * (1.f - ht1) + pobj[m][r] * ht1;
                orow[wcol0 + 16] = v1 * mk1;
            }
    }
}

extern "C" void kernel_launch(void* const* d_in, const int* in_sizes, int n_in,
                              void* d_out, int out_size, void* d_ws, size_t ws_size,
                              hipStream_t stream) {
    const float* fea_th  = (const float*)d_in[0];
    const float* fea_tw  = (const float*)d_in[1];
    const float* fea_obj = (const float*)d_in[2];
    const float* heatmap = (const float*)d_in[3];
    const float* mask    = (const float*)d_in[4];
    const float* W3d     = (const float*)d_in[5];
    const float* b3d     = (const float*)d_in[6];
    const float* W1d     = (const float*)d_in[7];
    const float* b1d     = (const float*)d_in[8];
    float* out = (float*)d_out;

    __bf16* wsA  = (__bf16*)d_ws;
    float* wsObj = (float*)((char*)d_ws + WS_OBJ_OFF);

    hipLaunchKernelGGL(prep_kernel, dim3(64), dim3(256), 0, stream,
                       fea_obj, W3d, W1d, b1d, wsA, wsObj);
    hipLaunchKernelGGL(main_kernel, dim3(512), dim3(256), 0, stream,
                       fea_th, fea_tw, heatmap, mask, b3d, wsA, wsObj, out);
}

// Round 5
// 83.183 us; speedup vs baseline: 2.0540x; 1.7200x over previous
//
#include <hip/hip_runtime.h>
#include <hip/hip_bf16.h>

// Problem constants
#define B_ 2
#define C_ 256
#define O_ 256
#define T_ 16
#define H_ 64
#define W_ 64

typedef __bf16 bf16x8 __attribute__((ext_vector_type(8)));
typedef float  f32x4  __attribute__((ext_vector_type(4)));

// ws layout:
//   [0, 131072)       : W3d bf16 pre-swizzled LDS image: [mt(2)][o_l*512 + ((cg*16)^((o_l&7)<<4))]
//   [131072, 163840)  : obj f32 [b][t][o]  (B*T*O = 8192 floats, contiguous in o)
#define WS_OBJ_OFF 131072

__device__ __forceinline__ void gload_lds16(const void* g, void* l) {
    __builtin_amdgcn_global_load_lds(
        (const __attribute__((address_space(1))) void*)g,
        (__attribute__((address_space(3))) void*)l, 16, 0, 0);
}

// ---------------- prep kernel ----------------
// blocks 0..31  : obj[b,t,o] = sum_c W1d[o,c]*fea_obj[b,c,t] + b1d[o]
// blocks 32..63 : W3d -> bf16 pre-swizzled image in ws ([128 o][256 c] rows of 512B,
//                 XOR-swizzle within each 128B sub-block)
__global__ __launch_bounds__(256) void prep_kernel(
    const float* __restrict__ fea_obj, const float* __restrict__ W3d,
    const float* __restrict__ W1d, const float* __restrict__ b1d,
    __bf16* __restrict__ wsA, float* __restrict__ wsObj) {
    const int bid = blockIdx.x;
    const int tid = threadIdx.x;
    if (bid < 32) {
        const int b = bid >> 4, t = bid & 15;
        __shared__ float fo[C_];
        fo[tid] = fea_obj[(b * C_ + tid) * T_ + t];
        __syncthreads();
        const int o = tid;
        const float4* wrow = (const float4*)(W1d + o * C_);
        float s = 0.f;
#pragma unroll 8
        for (int cq = 0; cq < C_ / 4; ++cq) {
            float4 wv = wrow[cq];
            s += wv.x * fo[cq * 4 + 0] + wv.y * fo[cq * 4 + 1] +
                 wv.z * fo[cq * 4 + 2] + wv.w * fo[cq * 4 + 3];
        }
        wsObj[(b * T_ + t) * O_ + o] = s + b1d[o];   // [b][t][o] layout
    } else {
        // 8192 groups of 8 consecutive c
        const int g = (bid - 32) * 256 + tid;
        const int o = g >> 5;        // 0..255
        const int cg = g & 31;       // group of 8 c's
        const float* sp = W3d + o * C_ + cg * 8;
        float4 a0 = *(const float4*)sp;
        float4 a1 = *(const float4*)(sp + 4);
        bf16x8 pk;
        pk[0] = (__bf16)a0.x; pk[1] = (__bf16)a0.y;
        pk[2] = (__bf16)a0.z; pk[3] = (__bf16)a0.w;
        pk[4] = (__bf16)a1.x; pk[5] = (__bf16)a1.y;
        pk[6] = (__bf16)a1.z; pk[7] = (__bf16)a1.w;
        const int mt = o >> 7, o_l = o & 127;
        const int dstb = mt * 65536 + o_l * 512 + ((cg * 16) ^ ((o_l & 7) << 4));
        *(bf16x8*)((char*)wsA + dstb) = pk;
    }
}

// ---------------- main kernel ----------------
// Grid 512 = hg(8) x mt(2) x bt(32). Block: 512 thr = 8 waves (2m x 4n).
// Wave tile: 64 o x 16 w. Per thread: twf[8] (32 VGPR), accA/accB (32),
// af transient (16) -> ~110 live regs, fits the 128-VGPR / 4-waves-per-EU
// budget (r2-r4 spilled at ~148 regs; allocator refused >128).
// Inner loop: per ks read af once, apply to TWO h values (halves A-read
// LDS traffic). pb/pobj read from LDS in epilogue (broadcast b128).
__global__ __attribute__((amdgpu_flat_work_group_size(512, 512)))
void main_kernel(
    const float* __restrict__ fea_th, const float* __restrict__ fea_tw,
    const float* __restrict__ heatmap, const float* __restrict__ mask,
    const float* __restrict__ b3d,
    const __bf16* __restrict__ wsA, const float* __restrict__ wsObj,
    float* __restrict__ out) {
    __shared__ __align__(16) char smem[75776];
    char*  sA   = smem;                      // [128 o][256 c] bf16, 512B rows, swizzled
    float* sTh  = (float*)(smem + 65536);    // [8 h][256 c] f32
    float* sPb  = (float*)(smem + 73728);    // [256] b3d
    float* sObj = (float*)(smem + 74752);    // [256] obj for this (b,t)

    const int tid  = threadIdx.x;
    const int lane = tid & 63;
    const int wv   = tid >> 6;       // 0..7
    const int wv_m = wv >> 2;        // 0..1 -> o offset *64
    const int wv_n = wv & 3;         // 0..3 -> w offset *16
    const int kgrp = lane >> 4;
    const int l15  = lane & 15;

    const int bid = blockIdx.x;
    const int hg = bid & 7, mt = (bid >> 3) & 1, bt = bid >> 4;
    const int b = bt >> 4, t = bt & 15, h0 = hg * 8;

    // ---- stage A: 64 KiB, pre-swizzled image, pure linear gload_lds ----
    const char* imgA = (const char*)wsA + mt * 65536;
#pragma unroll
    for (int q = 0; q < 8; ++q)
        gload_lds16(imgA + q * 8192 + tid * 16, sA + q * 8192 + tid * 16);

    // ---- stage th / pb / obj (first 256 threads) ----
    const float* objp = wsObj + (b * T_ + t) * O_;
    if (tid < 256) {
        const float* thp = fea_th + ((b * C_ + tid) * T_ + t) * H_ + h0;
        float4 v0 = *(const float4*)thp;
        float4 v1 = *(const float4*)(thp + 4);
        sTh[0 * 256 + tid] = v0.x;  sTh[1 * 256 + tid] = v0.y;
        sTh[2 * 256 + tid] = v0.z;  sTh[3 * 256 + tid] = v0.w;
        sTh[4 * 256 + tid] = v1.x;  sTh[5 * 256 + tid] = v1.y;
        sTh[6 * 256 + tid] = v1.z;  sTh[7 * 256 + tid] = v1.w;
        sPb[tid]  = b3d[tid];
        sObj[tid] = objp[tid];
    }

    // ---- tw -> register B-frags (bf16), loaded once: 32 VGPRs ----
    const int wcol0 = wv_n * 16 + l15;
    const float* twp = fea_tw + ((b * C_) * T_ + t) * W_;
    bf16x8 twf[8];
#pragma unroll
    for (int ks = 0; ks < 8; ++ks) {
        bf16x8 pk;
#pragma unroll
        for (int j = 0; j < 8; ++j) {
            const int c = ks * 32 + kgrp * 8 + j;
            pk[j] = (__bf16)twp[c * (T_ * W_) + wcol0];
        }
        twf[ks] = pk;
    }

    __syncthreads();   // drains gload_lds (vmcnt) + ds_writes; sA/sTh visible

    const int obase = mt * 128 + wv_m * 64 + kgrp * 4;   // per-lane o base (reg r adds +r, m adds +m*16)
    const int hmb   = (b * T_ + t) * (H_ * W_);
    const int swz   = (l15 & 7) << 4;
    const int arow  = (wv_m * 64 + l15) * 512;           // A byte row base (m adds m*16*512)

    for (int hp = 0; hp < 4; ++hp) {
        const int hA = hp * 2, hB = hA + 1;
        // prefetch heatmap/mask for both h (latency hidden by K-loop)
        const int rowA = hmb + (h0 + hA) * W_ + wcol0;
        const int rowB = hmb + (h0 + hB) * W_ + wcol0;
        const float htA = heatmap[rowA], mkA = mask[rowA];
        const float htB = heatmap[rowB], mkB = mask[rowB];

        f32x4 accA[4] = {}, accB[4] = {};
#pragma unroll
        for (int ks = 0; ks < 8; ++ks) {
            // A fragments (h-invariant: read once, use for both h)
            bf16x8 af[4];
            const int kbyte = (ks * 64 + kgrp * 16) ^ swz;
#pragma unroll
            for (int m = 0; m < 4; ++m)
                af[m] = *(const bf16x8*)(sA + arow + m * 8192 + kbyte);

            const bf16x8 tw8 = twf[ks];

            // h = hA
            {
                const float* thp = sTh + hA * 256 + ks * 32 + kgrp * 8;
                const f32x4 th0 = *(const f32x4*)thp;
                const f32x4 th1 = *(const f32x4*)(thp + 4);
                bf16x8 pk;
                pk[0] = (__bf16)((float)tw8[0] * th0[0]);
                pk[1] = (__bf16)((float)tw8[1] * th0[1]);
                pk[2] = (__bf16)((float)tw8[2] * th0[2]);
                pk[3] = (__bf16)((float)tw8[3] * th0[3]);
                pk[4] = (__bf16)((float)tw8[4] * th1[0]);
                pk[5] = (__bf16)((float)tw8[5] * th1[1]);
                pk[6] = (__bf16)((float)tw8[6] * th1[2]);
                pk[7] = (__bf16)((float)tw8[7] * th1[3]);
#pragma unroll
                for (int m = 0; m < 4; ++m)
                    accA[m] = __builtin_amdgcn_mfma_f32_16x16x32_bf16(
                        af[m], pk, accA[m], 0, 0, 0);
            }
            // h = hB
            {
                const float* thp = sTh + hB * 256 + ks * 32 + kgrp * 8;
                const f32x4 th0 = *(const f32x4*)thp;
                const f32x4 th1 = *(const f32x4*)(thp + 4);
                bf16x8 pk;
                pk[0] = (__bf16)((float)tw8[0] * th0[0]);
                pk[1] = (__bf16)((float)tw8[1] * th0[1]);
                pk[2] = (__bf16)((float)tw8[2] * th0[2]);
                pk[3] = (__bf16)((float)tw8[3] * th0[3]);
                pk[4] = (__bf16)((float)tw8[4] * th1[0]);
                pk[5] = (__bf16)((float)tw8[5] * th1[1]);
                pk[6] = (__bf16)((float)tw8[6] * th1[2]);
                pk[7] = (__bf16)((float)tw8[7] * th1[3]);
#pragma unroll
                for (int m = 0; m < 4; ++m)
                    accB[m] = __builtin_amdgcn_mfma_f32_16x16x32_bf16(
                        af[m], pk, accB[m], 0, 0, 0);
            }
        }

        // ---- fused epilogue (pb/pobj from LDS broadcast reads) ----
#pragma unroll
        for (int m = 0; m < 4; ++m) {
            const f32x4 pb4 = *(const f32x4*)(sPb + obase + m * 16);
            const f32x4 po4 = *(const f32x4*)(sObj + obase + m * 16);
#pragma unroll
            for (int r = 0; r < 4; ++r) {
                const int o = obase + m * 16 + r;
                float* orow = out + (((size_t)(b * O_ + o) * T_ + t) * H_ + h0) * W_;
                float vA = accA[m][r] + pb4[r];
                vA = vA * (1.f - htA) + po4[r] * htA;
                orow[hA * W_ + wcol0] = vA * mkA;
                float vB = accB[m][r] + pb4[r];
                vB = vB * (1.f - htB) + po4[r] * htB;
                orow[hB * W_ + wcol0] = vB * mkB;
            }
        }
    }
}

extern "C" void kernel_launch(void* const* d_in, const int* in_sizes, int n_in,
                              void* d_out, int out_size, void* d_ws, size_t ws_size,
                              hipStream_t stream) {
    const float* fea_th  = (const float*)d_in[0];
    const float* fea_tw  = (const float*)d_in[1];
    const float* fea_obj = (const float*)d_in[2];
    const float* heatmap = (const float*)d_in[3];
    const float* mask    = (const float*)d_in[4];
    const float* W3d     = (const float*)d_in[5];
    const float* b3d     = (const float*)d_in[6];
    const float* W1d     = (const float*)d_in[7];
    const float* b1d     = (const float*)d_in[8];
    float* out = (float*)d_out;

    __bf16* wsA  = (__bf16*)d_ws;
    float* wsObj = (float*)((char*)d_ws + WS_OBJ_OFF);

    hipLaunchKernelGGL(prep_kernel, dim3(64), dim3(256), 0, stream,
                       fea_obj, W3d, W1d, b1d, wsA, wsObj);
    hipLaunchKernelGGL(main_kernel, dim3(512), dim3(512), 0, stream,
                       fea_th, fea_tw, heatmap, mask, b3d, wsA, wsObj, out);
}

// Round 6
// 53.945 us; speedup vs baseline: 3.1672x; 1.5420x over previous
//
#include <hip/hip_runtime.h>
#include <hip/hip_bf16.h>

// Problem constants
#define B_ 2
#define C_ 256
#define O_ 256
#define T_ 16
#define H_ 64
#define W_ 64

typedef __bf16 bf16x8 __attribute__((ext_vector_type(8)));
typedef float  f32x4  __attribute__((ext_vector_type(4)));

// ws layout:
//   [0, 131072)       : W3d bf16 pre-swizzled LDS image: [mt(2)][o_l*512 + ((cg*16)^((o_l&7)<<4))]
//   [131072, 163840)  : obj f32 [b][t][o]  (B*T*O = 8192 floats, contiguous in o)
#define WS_OBJ_OFF 131072

__device__ __forceinline__ void gload_lds16(const void* g, void* l) {
    __builtin_amdgcn_global_load_lds(
        (const __attribute__((address_space(1))) void*)g,
        (__attribute__((address_space(3))) void*)l, 16, 0, 0);
}

// ---------------- prep kernel ----------------
// blocks 0..31  : obj[b,t,o] = sum_c W1d[o,c]*fea_obj[b,c,t] + b1d[o]
// blocks 32..63 : W3d -> bf16 pre-swizzled image in ws ([128 o][256 c] rows of 512B,
//                 XOR-swizzle within each 128B sub-block)
__global__ __launch_bounds__(256) void prep_kernel(
    const float* __restrict__ fea_obj, const float* __restrict__ W3d,
    const float* __restrict__ W1d, const float* __restrict__ b1d,
    __bf16* __restrict__ wsA, float* __restrict__ wsObj) {
    const int bid = blockIdx.x;
    const int tid = threadIdx.x;
    if (bid < 32) {
        const int b = bid >> 4, t = bid & 15;
        __shared__ float fo[C_];
        fo[tid] = fea_obj[(b * C_ + tid) * T_ + t];
        __syncthreads();
        const int o = tid;
        const float4* wrow = (const float4*)(W1d + o * C_);
        float s = 0.f;
#pragma unroll 8
        for (int cq = 0; cq < C_ / 4; ++cq) {
            float4 wv = wrow[cq];
            s += wv.x * fo[cq * 4 + 0] + wv.y * fo[cq * 4 + 1] +
                 wv.z * fo[cq * 4 + 2] + wv.w * fo[cq * 4 + 3];
        }
        wsObj[(b * T_ + t) * O_ + o] = s + b1d[o];   // [b][t][o] layout
    } else {
        // 8192 groups of 8 consecutive c
        const int g = (bid - 32) * 256 + tid;
        const int o = g >> 5;        // 0..255
        const int cg = g & 31;       // group of 8 c's
        const float* sp = W3d + o * C_ + cg * 8;
        float4 a0 = *(const float4*)sp;
        float4 a1 = *(const float4*)(sp + 4);
        bf16x8 pk;
        pk[0] = (__bf16)a0.x; pk[1] = (__bf16)a0.y;
        pk[2] = (__bf16)a0.z; pk[3] = (__bf16)a0.w;
        pk[4] = (__bf16)a1.x; pk[5] = (__bf16)a1.y;
        pk[6] = (__bf16)a1.z; pk[7] = (__bf16)a1.w;
        const int mt = o >> 7, o_l = o & 127;
        const int dstb = mt * 65536 + o_l * 512 + ((cg * 16) ^ ((o_l & 7) << 4));
        *(bf16x8*)((char*)wsA + dstb) = pk;
    }
}

// ---------------- main kernel ----------------
// Grid 512 = hg(8) x mt(2) x bt(32). Block: 512 thr = 8 waves (2m x 4n).
// Wave tile: 64 o x 16 w. Single-h inner loop (r5's h-pairing pushed the
// live set to ~140 regs and spilled against the structural 128-VGPR budget:
// 8-wave block + 75.8KB LDS -> 2 blk/CU -> 4 waves/SIMD -> 128 VGPR is the
// CORRECT allocator target; we must fit it).
// Per thread live: twf[8]=32, acc[4]=16, af[4]=16 transient, th 8, ~25 misc
// => ~105 regs, no spill.
__global__ __attribute__((amdgpu_flat_work_group_size(512, 512)))
void main_kernel(
    const float* __restrict__ fea_th, const float* __restrict__ fea_tw,
    const float* __restrict__ heatmap, const float* __restrict__ mask,
    const float* __restrict__ b3d,
    const __bf16* __restrict__ wsA, const float* __restrict__ wsObj,
    float* __restrict__ out) {
    __shared__ __align__(16) char smem[75776];
    char*  sA   = smem;                      // [128 o][256 c] bf16, 512B rows, swizzled
    float* sTh  = (float*)(smem + 65536);    // [8 h][256 c] f32
    float* sPb  = (float*)(smem + 73728);    // [256] b3d
    float* sObj = (float*)(smem + 74752);    // [256] obj for this (b,t)

    const int tid  = threadIdx.x;
    const int lane = tid & 63;
    const int wv   = tid >> 6;       // 0..7
    const int wv_m = wv >> 2;        // 0..1 -> o offset *64
    const int wv_n = wv & 3;         // 0..3 -> w offset *16
    const int kgrp = lane >> 4;
    const int l15  = lane & 15;

    const int bid = blockIdx.x;
    const int hg = bid & 7, mt = (bid >> 3) & 1, bt = bid >> 4;
    const int b = bt >> 4, t = bt & 15, h0 = hg * 8;

    // ---- stage A: 64 KiB, pre-swizzled image, pure linear gload_lds ----
    const char* imgA = (const char*)wsA + mt * 65536;
#pragma unroll
    for (int q = 0; q < 8; ++q)
        gload_lds16(imgA + q * 8192 + tid * 16, sA + q * 8192 + tid * 16);

    // ---- stage th / pb / obj (first 256 threads) ----
    const float* objp = wsObj + (b * T_ + t) * O_;
    if (tid < 256) {
        const float* thp = fea_th + ((b * C_ + tid) * T_ + t) * H_ + h0;
        float4 v0 = *(const float4*)thp;
        float4 v1 = *(const float4*)(thp + 4);
        sTh[0 * 256 + tid] = v0.x;  sTh[1 * 256 + tid] = v0.y;
        sTh[2 * 256 + tid] = v0.z;  sTh[3 * 256 + tid] = v0.w;
        sTh[4 * 256 + tid] = v1.x;  sTh[5 * 256 + tid] = v1.y;
        sTh[6 * 256 + tid] = v1.z;  sTh[7 * 256 + tid] = v1.w;
        sPb[tid]  = b3d[tid];
        sObj[tid] = objp[tid];
    }

    // ---- tw -> register B-frags (bf16), loaded once: 32 VGPRs ----
    const int wcol0 = wv_n * 16 + l15;
    const float* twp = fea_tw + ((b * C_) * T_ + t) * W_;
    bf16x8 twf[8];
#pragma unroll
    for (int ks = 0; ks < 8; ++ks) {
        bf16x8 pk;
#pragma unroll
        for (int j = 0; j < 8; ++j) {
            const int c = ks * 32 + kgrp * 8 + j;
            pk[j] = (__bf16)twp[c * (T_ * W_) + wcol0];
        }
        twf[ks] = pk;
    }

    __syncthreads();   // drains gload_lds (vmcnt) + ds_writes; sA/sTh visible

    const int obase = mt * 128 + wv_m * 64 + kgrp * 4;
    const int hmb   = (b * T_ + t) * (H_ * W_);
    const int swz   = (l15 & 7) << 4;
    const int arow  = (wv_m * 64 + l15) * 512;   // A byte row base (m adds m*8192)

    for (int hl = 0; hl < 8; ++hl) {
        // heatmap/mask for this h (issued at loop top, used in epilogue)
        const int row = hmb + (h0 + hl) * W_ + wcol0;
        const float ht = heatmap[row], mk = mask[row];

        f32x4 acc[4] = {};
#pragma unroll
        for (int ks = 0; ks < 8; ++ks) {
            bf16x8 af[4];
            const int kbyte = (ks * 64 + kgrp * 16) ^ swz;
#pragma unroll
            for (int m = 0; m < 4; ++m)
                af[m] = *(const bf16x8*)(sA + arow + m * 8192 + kbyte);

            const float* thp = sTh + hl * 256 + ks * 32 + kgrp * 8;
            const f32x4 th0 = *(const f32x4*)thp;
            const f32x4 th1 = *(const f32x4*)(thp + 4);

            const bf16x8 tw8 = twf[ks];
            bf16x8 pk;
            pk[0] = (__bf16)((float)tw8[0] * th0[0]);
            pk[1] = (__bf16)((float)tw8[1] * th0[1]);
            pk[2] = (__bf16)((float)tw8[2] * th0[2]);
            pk[3] = (__bf16)((float)tw8[3] * th0[3]);
            pk[4] = (__bf16)((float)tw8[4] * th1[0]);
            pk[5] = (__bf16)((float)tw8[5] * th1[1]);
            pk[6] = (__bf16)((float)tw8[6] * th1[2]);
            pk[7] = (__bf16)((float)tw8[7] * th1[3]);

#pragma unroll
            for (int m = 0; m < 4; ++m)
                acc[m] = __builtin_amdgcn_mfma_f32_16x16x32_bf16(
                    af[m], pk, acc[m], 0, 0, 0);
        }

        // ---- fused epilogue (pb/pobj broadcast from LDS) ----
#pragma unroll
        for (int m = 0; m < 4; ++m) {
            const f32x4 pb4 = *(const f32x4*)(sPb + obase + m * 16);
            const f32x4 po4 = *(const f32x4*)(sObj + obase + m * 16);
#pragma unroll
            for (int r = 0; r < 4; ++r) {
                const int o = obase + m * 16 + r;
                float* orow = out + (((size_t)(b * O_ + o) * T_ + t) * H_ + h0) * W_;
                float v = acc[m][r] + pb4[r];
                v = v * (1.f - ht) + po4[r] * ht;
                orow[hl * W_ + wcol0] = v * mk;
            }
        }
    }
}

extern "C" void kernel_launch(void* const* d_in, const int* in_sizes, int n_in,
                              void* d_out, int out_size, void* d_ws, size_t ws_size,
                              hipStream_t stream) {
    const float* fea_th  = (const float*)d_in[0];
    const float* fea_tw  = (const float*)d_in[1];
    const float* fea_obj = (const float*)d_in[2];
    const float* heatmap = (const float*)d_in[3];
    const float* mask    = (const float*)d_in[4];
    const float* W3d     = (const float*)d_in[5];
    const float* b3d     = (const float*)d_in[6];
    const float* W1d     = (const float*)d_in[7];
    const float* b1d     = (const float*)d_in[8];
    float* out = (float*)d_out;

    __bf16* wsA  = (__bf16*)d_ws;
    float* wsObj = (float*)((char*)d_ws + WS_OBJ_OFF);

    hipLaunchKernelGGL(prep_kernel, dim3(64), dim3(256), 0, stream,
                       fea_obj, W3d, W1d, b1d, wsA, wsObj);
    hipLaunchKernelGGL(main_kernel, dim3(512), dim3(512), 0, stream,
                       fea_th, fea_tw, heatmap, mask, b3d, wsA, wsObj, out);
}

// Round 7
// 48.248 us; speedup vs baseline: 3.5412x; 1.1181x over previous
//
#include <hip/hip_runtime.h>
#include <hip/hip_bf16.h>

// Problem constants
#define B_ 2
#define C_ 256
#define O_ 256
#define T_ 16
#define H_ 64
#define W_ 64

typedef __bf16 bf16x8 __attribute__((ext_vector_type(8)));
typedef float  f32x4  __attribute__((ext_vector_type(4)));

// ws layout:
//   [0, 131072)       : W3d bf16 LINEAR image [256 o][256 c] (512 B rows)
//   [131072, 163840)  : obj f32 [b][t][o]  (B*T*O = 8192 floats, contiguous in o)
#define WS_OBJ_OFF 131072

// ---------------- prep kernel ----------------
// blocks 0..31  : obj[b,t,o] = sum_c W1d[o,c]*fea_obj[b,c,t] + b1d[o]
// blocks 32..63 : W3d -> bf16 linear image in ws
__global__ __launch_bounds__(256) void prep_kernel(
    const float* __restrict__ fea_obj, const float* __restrict__ W3d,
    const float* __restrict__ W1d, const float* __restrict__ b1d,
    __bf16* __restrict__ wsW, float* __restrict__ wsObj) {
    const int bid = blockIdx.x;
    const int tid = threadIdx.x;
    if (bid < 32) {
        const int b = bid >> 4, t = bid & 15;
        __shared__ float fo[C_];
        fo[tid] = fea_obj[(b * C_ + tid) * T_ + t];
        __syncthreads();
        const int o = tid;
        const float4* wrow = (const float4*)(W1d + o * C_);
        float s = 0.f;
#pragma unroll 8
        for (int cq = 0; cq < C_ / 4; ++cq) {
            float4 wv = wrow[cq];
            s += wv.x * fo[cq * 4 + 0] + wv.y * fo[cq * 4 + 1] +
                 wv.z * fo[cq * 4 + 2] + wv.w * fo[cq * 4 + 3];
        }
        wsObj[(b * T_ + t) * O_ + o] = s + b1d[o];   // [b][t][o] layout
    } else {
        // 8192 groups of 8 consecutive c; linear [o][c] bf16 image
        const int g = (bid - 32) * 256 + tid;
        const int o = g >> 5;        // 0..255
        const int cg = g & 31;       // group of 8 c's
        const float* sp = W3d + o * C_ + cg * 8;
        float4 a0 = *(const float4*)sp;
        float4 a1 = *(const float4*)(sp + 4);
        bf16x8 pk;
        pk[0] = (__bf16)a0.x; pk[1] = (__bf16)a0.y;
        pk[2] = (__bf16)a0.z; pk[3] = (__bf16)a0.w;
        pk[4] = (__bf16)a1.x; pk[5] = (__bf16)a1.y;
        pk[6] = (__bf16)a1.z; pk[7] = (__bf16)a1.w;
        *(bf16x8*)((char*)wsW + o * 512 + cg * 16) = pk;
    }
}

// ---------------- main kernel ----------------
// Grid 512 = wb(2) x hg(8) x bt(32). Block: 512 thr = 8 waves.
// Wave tile 32o x 32w: wave wv owns o in [wv*32, wv*32+32). Block covers all
// 256 o x 32 w x 8 h. A (W3d) lives in REGISTERS: af[2][8] = 64 VGPR per
// lane (the wave's 32x256 bf16 panel) -> no LDS A-reads at all (r6's LDS
// bottleneck: 56 b128/wave/h, ~36us/CU > HBM floor).
// B (th*tw) built per h into 16KB swizzled LDS, double-buffered; 1 barrier/h.
__global__ __attribute__((amdgpu_flat_work_group_size(512, 512)))
void main_kernel(
    const float* __restrict__ fea_th, const float* __restrict__ fea_tw,
    const float* __restrict__ heatmap, const float* __restrict__ mask,
    const float* __restrict__ b3d,
    const __bf16* __restrict__ wsW, const float* __restrict__ wsObj,
    float* __restrict__ out) {
    __shared__ __align__(16) char smem[43008];
    char*  sB0  = smem;                      // [32 w][512 B] swizzled, buf 0
    char*  sB1  = smem + 16384;              // buf 1
    float* sTh  = (float*)(smem + 32768);    // [8 h][256 c] f32
    float* sPb  = (float*)(smem + 40960);    // [256] b3d
    float* sObj = (float*)(smem + 41984);    // [256] obj for this (b,t)

    const int tid  = threadIdx.x;
    const int lane = tid & 63;
    const int wv   = tid >> 6;       // 0..7 -> o base wv*32
    const int kgrp = lane >> 4;
    const int l15  = lane & 15;

    const int bid = blockIdx.x;
    const int wb = bid & 1, hg = (bid >> 1) & 7, bt = bid >> 4;
    const int b = bt >> 4, t = bt & 15;
    const int h0 = hg * 8, w0 = wb * 32;

    // ---- stage th / pb / obj (first 256 threads) ----
    const float* objp = wsObj + (b * T_ + t) * O_;
    if (tid < 256) {
        const float* thp = fea_th + ((b * C_ + tid) * T_ + t) * H_ + h0;
        float4 v0 = *(const float4*)thp;
        float4 v1 = *(const float4*)(thp + 4);
        sTh[0 * 256 + tid] = v0.x;  sTh[1 * 256 + tid] = v0.y;
        sTh[2 * 256 + tid] = v0.z;  sTh[3 * 256 + tid] = v0.w;
        sTh[4 * 256 + tid] = v1.x;  sTh[5 * 256 + tid] = v1.y;
        sTh[6 * 256 + tid] = v1.z;  sTh[7 * 256 + tid] = v1.w;
        sPb[tid]  = b3d[tid];
        sObj[tid] = objp[tid];
    }

    // ---- tw -> per-thread bf16 slice (w = w0 + (tid&31), c in [cs, cs+16)) ----
    const int wl = tid & 31;
    const int cs = (tid >> 5) * 16;
    bf16x8 twb0, twb1;
    {
        const float* twp = fea_tw + ((b * C_ + cs) * T_ + t) * W_ + w0 + wl;
#pragma unroll
        for (int j = 0; j < 8; ++j) twb0[j] = (__bf16)twp[j * (T_ * W_)];
#pragma unroll
        for (int j = 0; j < 8; ++j) twb1[j] = (__bf16)twp[(8 + j) * (T_ * W_)];
    }

    // ---- A panel -> registers: af[mf][ks], 64 VGPR ----
    bf16x8 af[2][8];
#pragma unroll
    for (int mf = 0; mf < 2; ++mf)
#pragma unroll
        for (int ks = 0; ks < 8; ++ks)
            af[mf][ks] = *(const bf16x8*)(
                wsW + (wv * 32 + mf * 16 + l15) * 256 + ks * 32 + kgrp * 8);

    const int swzW = (wl & 7) << 4;
    const int c0g  = (cs >> 3) * 16;   // byte col of this thread's first 8-group

    auto build = [&](int hl, char* dst) {
        const float* thp = sTh + hl * 256 + cs;
        const f32x4 t0 = *(const f32x4*)thp;
        const f32x4 t1 = *(const f32x4*)(thp + 4);
        const f32x4 t2 = *(const f32x4*)(thp + 8);
        const f32x4 t3 = *(const f32x4*)(thp + 12);
        bf16x8 z0, z1;
        z0[0] = (__bf16)((float)twb0[0] * t0[0]);
        z0[1] = (__bf16)((float)twb0[1] * t0[1]);
        z0[2] = (__bf16)((float)twb0[2] * t0[2]);
        z0[3] = (__bf16)((float)twb0[3] * t0[3]);
        z0[4] = (__bf16)((float)twb0[4] * t1[0]);
        z0[5] = (__bf16)((float)twb0[5] * t1[1]);
        z0[6] = (__bf16)((float)twb0[6] * t1[2]);
        z0[7] = (__bf16)((float)twb0[7] * t1[3]);
        z1[0] = (__bf16)((float)twb1[0] * t2[0]);
        z1[1] = (__bf16)((float)twb1[1] * t2[1]);
        z1[2] = (__bf16)((float)twb1[2] * t2[2]);
        z1[3] = (__bf16)((float)twb1[3] * t2[3]);
        z1[4] = (__bf16)((float)twb1[4] * t3[0]);
        z1[5] = (__bf16)((float)twb1[5] * t3[1]);
        z1[6] = (__bf16)((float)twb1[6] * t3[2]);
        z1[7] = (__bf16)((float)twb1[7] * t3[3]);
        *(bf16x8*)(dst + wl * 512 + (c0g ^ swzW))        = z0;
        *(bf16x8*)(dst + wl * 512 + ((c0g + 16) ^ swzW)) = z1;
    };

    __syncthreads();          // sTh ready
    build(0, sB0);
    __syncthreads();          // sB0 ready

    const int hmb  = (b * T_ + t) * (H_ * W_);
    const int swzR = (l15 & 7) << 4;
    const int ob0  = wv * 32 + kgrp * 4;

    for (int hl = 0; hl < 8; ++hl) {
        char* cur = (hl & 1) ? sB1 : sB0;
        if (hl < 7) build(hl + 1, (hl & 1) ? sB0 : sB1);

        const int hglb = h0 + hl;
        const int hrow = hmb + hglb * W_ + w0 + l15;
        const float ht0 = heatmap[hrow],      mk0 = mask[hrow];
        const float ht1 = heatmap[hrow + 16], mk1 = mask[hrow + 16];

        f32x4 acc[2][2] = {};
#pragma unroll
        for (int ks = 0; ks < 8; ++ks) {
            const int kb = ks * 64 + kgrp * 16;
            const bf16x8 b0 = *(const bf16x8*)(cur + l15 * 512 + (kb ^ swzR));
            const bf16x8 b1 = *(const bf16x8*)(cur + (16 + l15) * 512 + (kb ^ swzR));
            acc[0][0] = __builtin_amdgcn_mfma_f32_16x16x32_bf16(af[0][ks], b0, acc[0][0], 0, 0, 0);
            acc[0][1] = __builtin_amdgcn_mfma_f32_16x16x32_bf16(af[0][ks], b1, acc[0][1], 0, 0, 0);
            acc[1][0] = __builtin_amdgcn_mfma_f32_16x16x32_bf16(af[1][ks], b0, acc[1][0], 0, 0, 0);
            acc[1][1] = __builtin_amdgcn_mfma_f32_16x16x32_bf16(af[1][ks], b1, acc[1][1], 0, 0, 0);
        }

        // ---- fused epilogue ----
#pragma unroll
        for (int mf = 0; mf < 2; ++mf) {
            const f32x4 pb4 = *(const f32x4*)(sPb + ob0 + mf * 16);
            const f32x4 po4 = *(const f32x4*)(sObj + ob0 + mf * 16);
#pragma unroll
            for (int r = 0; r < 4; ++r) {
                const int o = ob0 + mf * 16 + r;
                float* orow = out + (((size_t)(b * O_ + o) * T_ + t) * H_ + hglb) * W_ + w0;
                float v0 = acc[mf][0][r] + pb4[r];
                v0 = v0 * (1.f - ht0) + po4[r] * ht0;
                orow[l15] = v0 * mk0;
                float v1 = acc[mf][1][r] + pb4[r];
                v1 = v1 * (1.f - ht1) + po4[r] * ht1;
                orow[16 + l15] = v1 * mk1;
            }
        }
        __syncthreads();   // all reads of `cur` done before hl+1 rebuilds it
    }
}

extern "C" void kernel_launch(void* const* d_in, const int* in_sizes, int n_in,
                              void* d_out, int out_size, void* d_ws, size_t ws_size,
                              hipStream_t stream) {
    const float* fea_th  = (const float*)d_in[0];
    const float* fea_tw  = (const float*)d_in[1];
    const float* fea_obj = (const float*)d_in[2];
    const float* heatmap = (const float*)d_in[3];
    const float* mask    = (const float*)d_in[4];
    const float* W3d     = (const float*)d_in[5];
    const float* b3d     = (const float*)d_in[6];
    const float* W1d     = (const float*)d_in[7];
    const float* b1d     = (const float*)d_in[8];
    float* out = (float*)d_out;

    __bf16* wsW  = (__bf16*)d_ws;
    float* wsObj = (float*)((char*)d_ws + WS_OBJ_OFF);

    hipLaunchKernelGGL(prep_kernel, dim3(64), dim3(256), 0, stream,
                       fea_obj, W3d, W1d, b1d, wsW, wsObj);
    hipLaunchKernelGGL(main_kernel, dim3(512), dim3(512), 0, stream,
                       fea_th, fea_tw, heatmap, mask, b3d, wsW, wsObj, out);
}